// Round 14
// baseline (204.013 us; speedup 1.0000x reference)
//
#include <hip/hip_runtime.h>
#include <hip/hip_bf16.h>
#include <stdint.h>

// Problem constants: B=8, N=4096, C=512, K=V=512, H=8, hk=hv=64, M = B*N = 32768

typedef __attribute__((ext_vector_type(8))) short short8;
typedef __attribute__((ext_vector_type(4))) float f32x4;
typedef __attribute__((ext_vector_type(4))) unsigned short us4;

__device__ __forceinline__ unsigned short f2bf(float f) {
  union { float f; unsigned u; } v; v.f = f;
  unsigned r = v.u + 0x7FFFu + ((v.u >> 16) & 1u);  // RNE
  return (unsigned short)(r >> 16);
}
__device__ __forceinline__ float bf2f(unsigned short u) {
  union { unsigned u; float f; } v; v.u = ((unsigned)u) << 16;
  return v.f;
}
__device__ __forceinline__ ushort2 pk2(float a, float b) {
  __hip_bfloat162 h = __float22bfloat162_rn(float2{a, b});
  return *reinterpret_cast<ushort2*>(&h);
}
__device__ __forceinline__ us4 cvt4(float4 a) {
  ushort2 c0 = pk2(a.x, a.y), c1 = pk2(a.z, a.w);
  us4 r; r[0] = c0.x; r[1] = c0.y; r[2] = c1.x; r[3] = c1.y;
  return r;
}
// async global->LDS, 16B per lane; lds base wave-uniform (HW: base + lane*16)
__device__ __forceinline__ void gload16(const void* g, void* l) {
  __builtin_amdgcn_global_load_lds(
      (const __attribute__((address_space(1))) void*)g,
      (__attribute__((address_space(3))) void*)l, 16, 0, 0);
}

// ---------------------------------------------------------------------------
// Transpose + bf16-convert the 4 weight matrices: Wt[w][out][in] = W[in][out].
// Block (0,0,3) additionally zeroes S (16 KB).
__global__ void prep_w(const float* __restrict__ Wk, const float* __restrict__ Wq,
                       const float* __restrict__ Wv, const float* __restrict__ Wr,
                       unsigned short* __restrict__ Wt, float* __restrict__ S) {
  __shared__ float tile[64][65];
  const int t = threadIdx.x;
  const int bx = blockIdx.x, by = blockIdx.y, w = blockIdx.z;
  if (w == 3 && bx == 0 && by == 0) {
#pragma unroll
    for (int i = 0; i < 16; ++i) S[i * 256 + t] = 0.f;
  }
  const float* W = (w == 0) ? Wk : (w == 1) ? Wq : (w == 2) ? Wv : Wr;
  unsigned short* O = Wt + (size_t)w * 512 * 512;
#pragma unroll
  for (int p = 0; p < 16; ++p) {
    int idx = p * 256 + t; int r = idx >> 6, c = idx & 63;
    tile[r][c] = W[(size_t)(by * 64 + r) * 512 + bx * 64 + c];
  }
  __syncthreads();
#pragma unroll
  for (int p = 0; p < 16; ++p) {
    int idx = p * 256 + t; int r = idx >> 6, c = idx & 63;
    O[(size_t)(bx * 64 + r) * 512 + by * 64 + c] = f2bf(tile[c][r]);
  }
}

// ---------------------------------------------------------------------------
// Streaming pre-pass: xb=bf16(x), yb=bf16(y), xyb=bf16(x+y).
// NEW: nontemporal stores — bypass L2/L3 so the 96MB of streaming writes go
// at full HBM write BW and stop evicting the L3-resident x,y inputs.
__global__ __launch_bounds__(256) void prep_xy(const float* __restrict__ x, const float* __restrict__ y,
                        unsigned short* __restrict__ xb, unsigned short* __restrict__ yb,
                        unsigned short* __restrict__ xyb) {
  const size_t i = ((size_t)blockIdx.x * 256 + threadIdx.x) * 4;
  float4 a = *(const float4*)(x + i);
  float4 b = *(const float4*)(y + i);
  float4 s{a.x + b.x, a.y + b.y, a.z + b.z, a.w + b.w};
  __builtin_nontemporal_store(cvt4(a), (us4*)(xb + i));
  __builtin_nontemporal_store(cvt4(b), (us4*)(yb + i));
  __builtin_nontemporal_store(cvt4(s), (us4*)(xyb + i));
}

// ---------------------------------------------------------------------------
// bf16 GEMM (R5/R10 skeleton, proven): 128x128 tile, BK=64, double-buffered
// LDS, counted vmcnt, raw s_barrier, XOR-swizzled LDS.
// MODE 0: epilogue exp(), TRANSPOSED out (KeT[b][k][tok]) + S atomic row-sums
// MODE 1: epilogue fused head-softmax (64 ch), row-major bf16 out
// MODE 3: final: B = Bmat + batch*512*512, fp32 row-major out + bias
template <int MODE>
__global__ __launch_bounds__(256) void gemm_bf16(const unsigned short* __restrict__ A,
                          const unsigned short* __restrict__ Bmat,
                          const float* __restrict__ bias, void* __restrict__ OutV,
                          float* __restrict__ S) {
  __shared__ __align__(16) unsigned short As[2][128][64];
  __shared__ __align__(16) unsigned short Bs[2][128][64];
  const int t = threadIdx.x, l = t & 63, w = t >> 6;
  const int lr = l & 15, lg = l >> 4;
  const int wr = w >> 1, wc = w & 1;
  const int bid = blockIdx.x;
  const int swz = (bid & 7) * 128 + (bid >> 3);  // bijective XCD swizzle (1024 % 8 == 0)
  const int tn = swz & 3, tm = swz >> 2;

  const unsigned short* Bbase = (MODE == 3) ? (Bmat + (size_t)(tm >> 5) * 262144) : Bmat;
  const int r0 = w * 8 + (l >> 3);
  const int su = ((l & 7) ^ (l >> 3)) * 8;
  const unsigned short* Ag = A + (size_t)(tm * 128 + r0) * 512 + su;
  const unsigned short* Bg = Bbase + (size_t)(tn * 128 + r0) * 512 + su;

  f32x4 acc[4][4] = {};

#define PSTAGE(buf, kt)                                                        \
  {                                                                            \
    _Pragma("unroll") for (int i = 0; i < 4; ++i) {                            \
      gload16(Ag + (size_t)i * 32 * 512 + (kt) * 64, &As[buf][i * 32 + w * 8][0]); \
      gload16(Bg + (size_t)i * 32 * 512 + (kt) * 64, &Bs[buf][i * 32 + w * 8][0]); \
    }                                                                          \
  }

  PSTAGE(0, 0)
  PSTAGE(1, 1)
  for (int kt = 0; kt < 8; ++kt) {
    const int cur = kt & 1;
    if (kt < 7) { asm volatile("s_waitcnt vmcnt(8)" ::: "memory"); }
    else        { asm volatile("s_waitcnt vmcnt(0)" ::: "memory"); }
    __builtin_amdgcn_s_barrier();
    asm volatile("" ::: "memory");
    __builtin_amdgcn_s_setprio(1);
#pragma unroll
    for (int kk = 0; kk < 2; ++kk) {
      short8 af[4], bf[4];
#pragma unroll
      for (int m = 0; m < 4; ++m)
        af[m] = *(const short8*)&As[cur][wr * 64 + m * 16 + lr][((kk * 4 + lg) ^ (lr & 7)) * 8];
#pragma unroll
      for (int n = 0; n < 4; ++n)
        bf[n] = *(const short8*)&Bs[cur][wc * 64 + n * 16 + lr][((kk * 4 + lg) ^ (lr & 7)) * 8];
#pragma unroll
      for (int m = 0; m < 4; ++m)
#pragma unroll
        for (int n = 0; n < 4; ++n)
          acc[m][n] = __builtin_amdgcn_mfma_f32_16x16x32_bf16(af[m], bf[n], acc[m][n], 0, 0, 0);
    }
    __builtin_amdgcn_s_setprio(0);
    asm volatile("" ::: "memory");
    __builtin_amdgcn_s_barrier();
    asm volatile("" ::: "memory");
    if (kt < 6) PSTAGE(cur, kt + 2)
  }
#undef PSTAGE

  // ---- epilogue ----
  const int c_base = tn * 128 + wc * 64;
  const int r_base = tm * 128 + wr * 64;
  float bv_[4];
#pragma unroll
  for (int n = 0; n < 4; ++n) bv_[n] = bias[c_base + n * 16 + lr];

  if (MODE == 1) {
    unsigned short* Out = (unsigned short*)OutV;
#pragma unroll
    for (int m = 0; m < 4; ++m) {
#pragma unroll
      for (int j = 0; j < 4; ++j) {
        float a0 = acc[m][0][j] + bv_[0], a1 = acc[m][1][j] + bv_[1];
        float a2 = acc[m][2][j] + bv_[2], a3 = acc[m][3][j] + bv_[3];
        float mx = fmaxf(fmaxf(a0, a1), fmaxf(a2, a3));
#pragma unroll
        for (int o = 1; o < 16; o <<= 1) mx = fmaxf(mx, __shfl_xor(mx, o));
        float e0 = __expf(a0 - mx), e1 = __expf(a1 - mx);
        float e2 = __expf(a2 - mx), e3 = __expf(a3 - mx);
        float s = e0 + e1 + e2 + e3;
#pragma unroll
        for (int o = 1; o < 16; o <<= 1) s += __shfl_xor(s, o);
        const float rs = 1.0f / s;
        const int row = r_base + m * 16 + lg * 4 + j;
        Out[(size_t)row * 512 + c_base + 0 * 16 + lr] = f2bf(e0 * rs);
        Out[(size_t)row * 512 + c_base + 1 * 16 + lr] = f2bf(e1 * rs);
        Out[(size_t)row * 512 + c_base + 2 * 16 + lr] = f2bf(e2 * rs);
        Out[(size_t)row * 512 + c_base + 3 * 16 + lr] = f2bf(e3 * rs);
      }
    }
  } else if (MODE == 3) {
    float* Out = (float*)OutV;
#pragma unroll
    for (int n = 0; n < 4; ++n) {
      const int col = c_base + n * 16 + lr;
#pragma unroll
      for (int m = 0; m < 4; ++m) {
        const int row = r_base + m * 16 + lg * 4;
#pragma unroll
        for (int j = 0; j < 4; ++j)
          Out[(size_t)(row + j) * 512 + col] = acc[m][n][j] + bv_[n];
      }
    }
  } else {  // MODE 0
    unsigned short* Out = (unsigned short*)OutV;
    const int b = (tm * 128) >> 12;
#pragma unroll
    for (int n = 0; n < 4; ++n) {
      const int col = c_base + n * 16 + lr;
      float srow = 0.f;
#pragma unroll
      for (int m = 0; m < 4; ++m) {
        const int row = r_base + m * 16 + lg * 4;
        const int nl = row & 4095;
        us4 v;
#pragma unroll
        for (int j = 0; j < 4; ++j) {
          float f = __expf(acc[m][n][j] + bv_[n]);
          srow += f;
          v[j] = f2bf(f);
        }
        *(us4*)&Out[((size_t)(b * 512 + col)) * 4096 + nl] = v;
      }
      srow += __shfl_xor(srow, 16);
      srow += __shfl_xor(srow, 32);
      if (lg == 0) atomicAdd(&S[b * 512 + col], srow);
    }
  }
}

// ---------------------------------------------------------------------------
// 256x256-tile deep-pipelined GEMM for the V projection (R12-proven).
// BK=32, 512 threads (8 waves, 2M x 4N, 128x64 out/wave), TRIPLE-buffered
// 32KB K-tile LDS (96 KB), 4 phases/K-tile, counted vmcnt(4) per K-tile.
__global__ __launch_bounds__(512) void gemm_v256(const unsigned short* __restrict__ A,
                          const unsigned short* __restrict__ Bt,
                          const float* __restrict__ bias,
                          unsigned short* __restrict__ Out) {
  __shared__ __align__(16) unsigned short lds[3][4][64][64];  // 96 KB
  const int t = threadIdx.x, l = t & 63, w = t >> 6;
  const int lr = l & 15, lg = l >> 4;
  const int wr = w >> 2, wc = w & 3;
  const int bid = blockIdx.x;
  const int swz = (bid & 7) * 32 + (bid >> 3);    // XCD swizzle (256 % 8 == 0)
  const int tn = swz & 1, tm = swz >> 1;

  const int swu = (t & 7) ^ ((t >> 3) & 7);
  const int row_g = 2 * (t >> 3) + (swu >> 2);
  const int col8 = (swu & 3) * 8;
  const unsigned short* Asrc = A + (size_t)(tm * 256 + row_g) * 512 + col8;
  const unsigned short* Bsrc = Bt + (size_t)(tn * 256 + row_g) * 512 + col8;

  const int rhalf = lr >> 1;
  const int fu = (((lr & 1) * 4 + lg) ^ rhalf) * 8;

  f32x4 acc[8][4] = {};

#define VSTAGE(blk, kt, buf)                                                   \
  {                                                                            \
    const unsigned short* s_ =                                                 \
        (((blk) < 2) ? (Asrc + (size_t)(blk) * 128 * 512)                      \
                     : (Bsrc + (size_t)((blk) - 2) * 128 * 512)) + (kt) * 32;  \
    gload16(s_, &lds[buf][blk][w * 8][0]);                                     \
  }

  VSTAGE(0, 0, 0) VSTAGE(1, 0, 0) VSTAGE(2, 0, 0) VSTAGE(3, 0, 0)
  VSTAGE(0, 1, 1) VSTAGE(1, 1, 1) VSTAGE(2, 1, 1) VSTAGE(3, 1, 1)
  asm volatile("s_waitcnt vmcnt(4)" ::: "memory");
  __builtin_amdgcn_s_barrier();
  asm volatile("" ::: "memory");

  for (int it = 0; it < 16; ++it) {
    const int cur = it % 3, stb = (it + 2) % 3;
    const int ktn = it + 2;
#pragma unroll
    for (int q = 0; q < 4; ++q) {
      const int mh = q >> 1, nh = q & 1;
      short8 af[4], bf[2];
#pragma unroll
      for (int mp = 0; mp < 4; ++mp)
        af[mp] = *(const short8*)&lds[cur][wr][(mh * 4 + mp) * 8 + rhalf][fu];
#pragma unroll
      for (int np = 0; np < 2; ++np)
        bf[np] = *(const short8*)&lds[cur][2 + (wc >> 1)][(wc & 1) * 32 + (nh * 2 + np) * 8 + rhalf][fu];
      if (it < 14) VSTAGE(q, ktn, stb)
      __builtin_amdgcn_s_setprio(1);
#pragma unroll
      for (int mp = 0; mp < 4; ++mp)
#pragma unroll
        for (int np = 0; np < 2; ++np)
          acc[mh * 4 + mp][nh * 2 + np] = __builtin_amdgcn_mfma_f32_16x16x32_bf16(
              af[mp], bf[np], acc[mh * 4 + mp][nh * 2 + np], 0, 0, 0);
      __builtin_amdgcn_s_setprio(0);
      asm volatile("" ::: "memory");
      if (q == 3) {
        if (it < 14) { asm volatile("s_waitcnt vmcnt(4)" ::: "memory"); }
        else         { asm volatile("s_waitcnt vmcnt(0)" ::: "memory"); }
      }
      __builtin_amdgcn_s_barrier();
      asm volatile("" ::: "memory");
    }
  }
#undef VSTAGE

  asm volatile("s_waitcnt vmcnt(0) lgkmcnt(0)" ::: "memory");
  const int c_base = tn * 256 + wc * 64;
  const int r_base = tm * 256 + wr * 128;
  const int b = r_base >> 12;
  float bv_[4];
#pragma unroll
  for (int n = 0; n < 4; ++n) bv_[n] = bias[c_base + n * 16 + lr];
#pragma unroll
  for (int n = 0; n < 4; ++n) {
    const int col = c_base + n * 16 + lr;
#pragma unroll
    for (int m = 0; m < 8; ++m) {
      const int row = r_base + m * 16 + lg * 4;
      const int nl = row & 4095;
      us4 v;
#pragma unroll
      for (int j = 0; j < 4; ++j) v[j] = f2bf(acc[m][n][j] + bv_[n]);
      *(us4*)&Out[((size_t)(b * 512 + col)) * 4096 + nl] = v;
    }
  }
}

// ---------------------------------------------------------------------------
// Partial context: D[v][k] = sum_tok VT[v][tok] * KeT[k][tok] over a 1024-token chunk.
__global__ void context_partial(const unsigned short* __restrict__ KeT,
                                const unsigned short* __restrict__ VT,
                                float* __restrict__ cp) {
  const int t = threadIdx.x, l = t & 63, w = t >> 6;
  const int lr = l & 15, lg = l >> 4;
  const int ch = blockIdx.x, h = blockIdx.y, b = blockIdx.z;
  const unsigned short* Kp = KeT + ((size_t)b * 512 + h * 64) * 4096;
  const unsigned short* Vp = VT + ((size_t)b * 512 + h * 64) * 4096;
  const int tok_w = ch * 1024 + w * 256;
  f32x4 acc[4][4] = {};
  for (int s = 0; s < 8; ++s) {
    const int tok = tok_w + s * 32 + lg * 8;
    short8 a[4], kf[4];
#pragma unroll
    for (int m = 0; m < 4; ++m) a[m] = *(const short8*)&Vp[(size_t)(m * 16 + lr) * 4096 + tok];
#pragma unroll
    for (int n = 0; n < 4; ++n) kf[n] = *(const short8*)&Kp[(size_t)(n * 16 + lr) * 4096 + tok];
#pragma unroll
    for (int m = 0; m < 4; ++m)
#pragma unroll
      for (int n = 0; n < 4; ++n)
        acc[m][n] = __builtin_amdgcn_mfma_f32_16x16x32_bf16(a[m], kf[n], acc[m][n], 0, 0, 0);
  }
  __shared__ float red[4][64][64];
#pragma unroll
  for (int m = 0; m < 4; ++m)
#pragma unroll
    for (int n = 0; n < 4; ++n)
#pragma unroll
      for (int j = 0; j < 4; ++j)
        red[w][m * 16 + lg * 4 + j][n * 16 + lr] = acc[m][n][j];
  __syncthreads();
  const int blk = (b * 8 + h) * 4 + ch;
  float* o = cp + (size_t)blk * 4096;
  for (int i = 0; i < 16; ++i) {
    int e = i * 256 + t;
    int v = e >> 6, k = e & 63;
    o[e] = red[0][v][k] + red[1][v][k] + red[2][v][k] + red[3][v][k];
  }
}

// ---------------------------------------------------------------------------
// Fused ctx_reduce + ctx_mm (R9, proven): per block (cc,h,b).
__global__ __launch_bounds__(256) void ctx_mm2(const float* __restrict__ cp,
                      const float* __restrict__ S, const unsigned short* __restrict__ Wrt,
                      unsigned short* __restrict__ MT) {
  __shared__ __align__(16) unsigned short ctx_lds[64][72];  // +8 pad
  const int t = threadIdx.x, l = t & 63, w = t >> 6;
  const int lr = l & 15, lg = l >> 4;
  const int cc = blockIdx.x, h = blockIdx.y, b = blockIdx.z;
  const int bh = b * 8 + h;

  const int k = t & 63, vg = t >> 6;
  const float rs = 1.0f / S[bh * 64 + k];
  const float* pb = cp + (size_t)bh * 4 * 4096 + k;
#pragma unroll
  for (int half = 0; half < 2; ++half) {
    short8 pkv;
#pragma unroll
    for (int i = 0; i < 8; ++i) {
      const int v = vg * 16 + half * 8 + i;
      const size_t e = (size_t)v * 64;
      float vsum = pb[e] + pb[4096 + e] + pb[8192 + e] + pb[12288 + e];
      pkv[i] = (short)f2bf(vsum * rs);
    }
    *(short8*)&ctx_lds[k][vg * 16 + half * 8] = pkv;
  }
  __syncthreads();

  const int c0 = cc * 128 + w * 32;
  f32x4 acc[4][2] = {};
#pragma unroll
  for (int kk = 0; kk < 2; ++kk) {
    const int vb = kk * 32 + lg * 8;
    short8 a[4], bfr[2];
#pragma unroll
    for (int m = 0; m < 4; ++m) a[m] = *(const short8*)&ctx_lds[m * 16 + lr][vb];
#pragma unroll
    for (int n = 0; n < 2; ++n)
      bfr[n] = *(const short8*)&Wrt[(size_t)(c0 + n * 16 + lr) * 512 + h * 64 + vb];
#pragma unroll
    for (int m = 0; m < 4; ++m)
#pragma unroll
      for (int n = 0; n < 2; ++n)
        acc[m][n] = __builtin_amdgcn_mfma_f32_16x16x32_bf16(a[m], bfr[n], acc[m][n], 0, 0, 0);
  }
#pragma unroll
  for (int n = 0; n < 2; ++n) {
    const int c = c0 + n * 16 + lr;
#pragma unroll
    for (int m = 0; m < 4; ++m) {
      const int kq = m * 16 + lg * 4;
      us4 v;
#pragma unroll
      for (int j = 0; j < 4; ++j) v[j] = f2bf(acc[m][n][j]);
      *(us4*)&MT[((size_t)b * 512 + c) * 512 + h * 64 + kq] = v;
    }
  }
}

// ---------------------------------------------------------------------------
extern "C" void kernel_launch(void* const* d_in, const int* in_sizes, int n_in,
                              void* d_out, int out_size, void* d_ws, size_t ws_size,
                              hipStream_t stream) {
  (void)in_sizes; (void)n_in; (void)out_size; (void)ws_size;
  const float* x  = (const float*)d_in[0];
  const float* y  = (const float*)d_in[1];
  const float* Wk = (const float*)d_in[2];
  const float* bk = (const float*)d_in[3];
  const float* Wq = (const float*)d_in[4];
  const float* bq = (const float*)d_in[5];
  const float* Wv = (const float*)d_in[6];
  const float* bv = (const float*)d_in[7];
  const float* Wr = (const float*)d_in[8];
  const float* br = (const float*)d_in[9];
  float* out = (float*)d_out;

  char* ws = (char*)d_ws;
  unsigned short* Wt   = (unsigned short*)(ws + 0);            //   2 MB: 4x [512][512] bf16
  unsigned short* xb   = (unsigned short*)(ws + 2097152);      //  32 MB: bf16(x)
  unsigned short* yb   = (unsigned short*)(ws + 35651584);     //  32 MB: bf16(y)
  unsigned short* xyb  = (unsigned short*)(ws + 69206016);     //  32 MB: bf16(x+y); reused as Qp
  unsigned short* KeT  = (unsigned short*)(ws + 102760448);    //  32 MB: [B][512][4096] bf16
  unsigned short* VT   = (unsigned short*)(ws + 136314880);    //  32 MB: [B][512][4096] bf16
  float* S             = (float*)(ws + 169869312);             //  16 KB
  float* cp            = (float*)(ws + 169885696);             //   4 MB
  unsigned short* MT   = (unsigned short*)(ws + 174080000);    //   4 MB (ends ~178.3 MB)
  unsigned short* Qp   = xyb;                                  // xyb dead after gemm_bf16<0>

  prep_w<<<dim3(8, 8, 4), 256, 0, stream>>>(Wk, Wq, Wv, Wr, Wt, S);
  prep_xy<<<16384, 256, 0, stream>>>(x, y, xb, yb, xyb);
  gemm_bf16<0><<<1024, 256, 0, stream>>>(xyb, Wt, bk, KeT, S);
  gemm_v256<<<256, 512, 0, stream>>>(xb, Wt + 2 * 262144, bv, VT);
  gemm_bf16<1><<<1024, 256, 0, stream>>>(yb, Wt + 262144, bq, Qp, nullptr);
  context_partial<<<dim3(4, 8, 8), 256, 0, stream>>>(KeT, VT, cp);
  ctx_mm2<<<dim3(4, 8, 8), 256, 0, stream>>>(cp, S, Wt + 3 * 262144, MT);
  gemm_bf16<3><<<1024, 256, 0, stream>>>(Qp, MT, br, out, nullptr);
}

// Round 15
// 182.622 us; speedup vs baseline: 1.1171x; 1.1171x over previous
//
#include <hip/hip_runtime.h>
#include <hip/hip_bf16.h>
#include <stdint.h>

// Problem constants: B=8, N=4096, C=512, K=V=512, H=8, hk=hv=64, M = B*N = 32768
// R15 = exact revert to the R12 configuration (session-best: 183.0 us).

typedef __attribute__((ext_vector_type(8))) short short8;
typedef __attribute__((ext_vector_type(4))) float f32x4;
typedef __attribute__((ext_vector_type(4))) unsigned short us4;

__device__ __forceinline__ unsigned short f2bf(float f) {
  union { float f; unsigned u; } v; v.f = f;
  unsigned r = v.u + 0x7FFFu + ((v.u >> 16) & 1u);  // RNE
  return (unsigned short)(r >> 16);
}
__device__ __forceinline__ float bf2f(unsigned short u) {
  union { unsigned u; float f; } v; v.u = ((unsigned)u) << 16;
  return v.f;
}
__device__ __forceinline__ ushort2 pk2(float a, float b) {
  __hip_bfloat162 h = __float22bfloat162_rn(float2{a, b});
  return *reinterpret_cast<ushort2*>(&h);
}
__device__ __forceinline__ us4 cvt4(float4 a) {
  ushort2 c0 = pk2(a.x, a.y), c1 = pk2(a.z, a.w);
  us4 r; r[0] = c0.x; r[1] = c0.y; r[2] = c1.x; r[3] = c1.y;
  return r;
}
// async global->LDS, 16B per lane; lds base wave-uniform (HW: base + lane*16)
__device__ __forceinline__ void gload16(const void* g, void* l) {
  __builtin_amdgcn_global_load_lds(
      (const __attribute__((address_space(1))) void*)g,
      (__attribute__((address_space(3))) void*)l, 16, 0, 0);
}

// ---------------------------------------------------------------------------
// Transpose + bf16-convert the 4 weight matrices: Wt[w][out][in] = W[in][out].
// Block (0,0,3) additionally zeroes S (16 KB).
__global__ void prep_w(const float* __restrict__ Wk, const float* __restrict__ Wq,
                       const float* __restrict__ Wv, const float* __restrict__ Wr,
                       unsigned short* __restrict__ Wt, float* __restrict__ S) {
  __shared__ float tile[64][65];
  const int t = threadIdx.x;
  const int bx = blockIdx.x, by = blockIdx.y, w = blockIdx.z;
  if (w == 3 && bx == 0 && by == 0) {
#pragma unroll
    for (int i = 0; i < 16; ++i) S[i * 256 + t] = 0.f;
  }
  const float* W = (w == 0) ? Wk : (w == 1) ? Wq : (w == 2) ? Wv : Wr;
  unsigned short* O = Wt + (size_t)w * 512 * 512;
#pragma unroll
  for (int p = 0; p < 16; ++p) {
    int idx = p * 256 + t; int r = idx >> 6, c = idx & 63;
    tile[r][c] = W[(size_t)(by * 64 + r) * 512 + bx * 64 + c];
  }
  __syncthreads();
#pragma unroll
  for (int p = 0; p < 16; ++p) {
    int idx = p * 256 + t; int r = idx >> 6, c = idx & 63;
    O[(size_t)(bx * 64 + r) * 512 + by * 64 + c] = f2bf(tile[c][r]);
  }
}

// ---------------------------------------------------------------------------
// Streaming pre-pass: xb=bf16(x), yb=bf16(y), xyb=bf16(x+y). (At the
// mixed-stream HW floor ~62-65us; seven variants measured invariant-or-worse.
// Plain cached stores: downstream GEMMs hit xb/yb/xyb in L3 — R14 proved
// nontemporal stores cost ~20us downstream.)
__global__ __launch_bounds__(256) void prep_xy(const float* __restrict__ x, const float* __restrict__ y,
                        unsigned short* __restrict__ xb, unsigned short* __restrict__ yb,
                        unsigned short* __restrict__ xyb) {
  const size_t i = ((size_t)blockIdx.x * 256 + threadIdx.x) * 4;
  float4 a = *(const float4*)(x + i);
  float4 b = *(const float4*)(y + i);
  float4 s{a.x + b.x, a.y + b.y, a.z + b.z, a.w + b.w};
  *(us4*)(xb + i) = cvt4(a);
  *(us4*)(yb + i) = cvt4(b);
  *(us4*)(xyb + i) = cvt4(s);
}

// ---------------------------------------------------------------------------
// bf16 GEMM (R5/R10 skeleton, proven): 128x128 tile, BK=64, double-buffered
// LDS, counted vmcnt, raw s_barrier, XOR-swizzled LDS.
// MODE 0: epilogue exp(), TRANSPOSED out (KeT[b][k][tok]) + S atomic row-sums
// MODE 1: epilogue fused head-softmax (64 ch), row-major bf16 out
// MODE 3: final: B = Bmat + batch*512*512, fp32 row-major out + bias
template <int MODE>
__global__ __launch_bounds__(256) void gemm_bf16(const unsigned short* __restrict__ A,
                          const unsigned short* __restrict__ Bmat,
                          const float* __restrict__ bias, void* __restrict__ OutV,
                          float* __restrict__ S) {
  __shared__ __align__(16) unsigned short As[2][128][64];
  __shared__ __align__(16) unsigned short Bs[2][128][64];
  const int t = threadIdx.x, l = t & 63, w = t >> 6;
  const int lr = l & 15, lg = l >> 4;
  const int wr = w >> 1, wc = w & 1;
  const int bid = blockIdx.x;
  const int swz = (bid & 7) * 128 + (bid >> 3);  // bijective XCD swizzle (1024 % 8 == 0)
  const int tn = swz & 3, tm = swz >> 2;

  const unsigned short* Bbase = (MODE == 3) ? (Bmat + (size_t)(tm >> 5) * 262144) : Bmat;
  const int r0 = w * 8 + (l >> 3);
  const int su = ((l & 7) ^ (l >> 3)) * 8;
  const unsigned short* Ag = A + (size_t)(tm * 128 + r0) * 512 + su;
  const unsigned short* Bg = Bbase + (size_t)(tn * 128 + r0) * 512 + su;

  f32x4 acc[4][4] = {};

#define PSTAGE(buf, kt)                                                        \
  {                                                                            \
    _Pragma("unroll") for (int i = 0; i < 4; ++i) {                            \
      gload16(Ag + (size_t)i * 32 * 512 + (kt) * 64, &As[buf][i * 32 + w * 8][0]); \
      gload16(Bg + (size_t)i * 32 * 512 + (kt) * 64, &Bs[buf][i * 32 + w * 8][0]); \
    }                                                                          \
  }

  PSTAGE(0, 0)
  PSTAGE(1, 1)
  for (int kt = 0; kt < 8; ++kt) {
    const int cur = kt & 1;
    if (kt < 7) { asm volatile("s_waitcnt vmcnt(8)" ::: "memory"); }
    else        { asm volatile("s_waitcnt vmcnt(0)" ::: "memory"); }
    __builtin_amdgcn_s_barrier();
    asm volatile("" ::: "memory");
    __builtin_amdgcn_s_setprio(1);
#pragma unroll
    for (int kk = 0; kk < 2; ++kk) {
      short8 af[4], bf[4];
#pragma unroll
      for (int m = 0; m < 4; ++m)
        af[m] = *(const short8*)&As[cur][wr * 64 + m * 16 + lr][((kk * 4 + lg) ^ (lr & 7)) * 8];
#pragma unroll
      for (int n = 0; n < 4; ++n)
        bf[n] = *(const short8*)&Bs[cur][wc * 64 + n * 16 + lr][((kk * 4 + lg) ^ (lr & 7)) * 8];
#pragma unroll
      for (int m = 0; m < 4; ++m)
#pragma unroll
        for (int n = 0; n < 4; ++n)
          acc[m][n] = __builtin_amdgcn_mfma_f32_16x16x32_bf16(af[m], bf[n], acc[m][n], 0, 0, 0);
    }
    __builtin_amdgcn_s_setprio(0);
    asm volatile("" ::: "memory");
    __builtin_amdgcn_s_barrier();
    asm volatile("" ::: "memory");
    if (kt < 6) PSTAGE(cur, kt + 2)
  }
#undef PSTAGE

  // ---- epilogue ----
  const int c_base = tn * 128 + wc * 64;
  const int r_base = tm * 128 + wr * 64;
  float bv_[4];
#pragma unroll
  for (int n = 0; n < 4; ++n) bv_[n] = bias[c_base + n * 16 + lr];

  if (MODE == 1) {
    unsigned short* Out = (unsigned short*)OutV;
#pragma unroll
    for (int m = 0; m < 4; ++m) {
#pragma unroll
      for (int j = 0; j < 4; ++j) {
        float a0 = acc[m][0][j] + bv_[0], a1 = acc[m][1][j] + bv_[1];
        float a2 = acc[m][2][j] + bv_[2], a3 = acc[m][3][j] + bv_[3];
        float mx = fmaxf(fmaxf(a0, a1), fmaxf(a2, a3));
#pragma unroll
        for (int o = 1; o < 16; o <<= 1) mx = fmaxf(mx, __shfl_xor(mx, o));
        float e0 = __expf(a0 - mx), e1 = __expf(a1 - mx);
        float e2 = __expf(a2 - mx), e3 = __expf(a3 - mx);
        float s = e0 + e1 + e2 + e3;
#pragma unroll
        for (int o = 1; o < 16; o <<= 1) s += __shfl_xor(s, o);
        const float rs = 1.0f / s;
        const int row = r_base + m * 16 + lg * 4 + j;
        Out[(size_t)row * 512 + c_base + 0 * 16 + lr] = f2bf(e0 * rs);
        Out[(size_t)row * 512 + c_base + 1 * 16 + lr] = f2bf(e1 * rs);
        Out[(size_t)row * 512 + c_base + 2 * 16 + lr] = f2bf(e2 * rs);
        Out[(size_t)row * 512 + c_base + 3 * 16 + lr] = f2bf(e3 * rs);
      }
    }
  } else if (MODE == 3) {
    float* Out = (float*)OutV;
#pragma unroll
    for (int n = 0; n < 4; ++n) {
      const int col = c_base + n * 16 + lr;
#pragma unroll
      for (int m = 0; m < 4; ++m) {
        const int row = r_base + m * 16 + lg * 4;
#pragma unroll
        for (int j = 0; j < 4; ++j)
          Out[(size_t)(row + j) * 512 + col] = acc[m][n][j] + bv_[n];
      }
    }
  } else {  // MODE 0
    unsigned short* Out = (unsigned short*)OutV;
    const int b = (tm * 128) >> 12;
#pragma unroll
    for (int n = 0; n < 4; ++n) {
      const int col = c_base + n * 16 + lr;
      float srow = 0.f;
#pragma unroll
      for (int m = 0; m < 4; ++m) {
        const int row = r_base + m * 16 + lg * 4;
        const int nl = row & 4095;
        us4 v;
#pragma unroll
        for (int j = 0; j < 4; ++j) {
          float f = __expf(acc[m][n][j] + bv_[n]);
          srow += f;
          v[j] = f2bf(f);
        }
        *(us4*)&Out[((size_t)(b * 512 + col)) * 4096 + nl] = v;
      }
      srow += __shfl_xor(srow, 16);
      srow += __shfl_xor(srow, 32);
      if (lg == 0) atomicAdd(&S[b * 512 + col], srow);
    }
  }
}

// ---------------------------------------------------------------------------
// 256x256-tile deep-pipelined GEMM for the V projection (R12-proven, A/B win).
// BK=32, 512 threads (8 waves, 2M x 4N, 128x64 out/wave), TRIPLE-buffered
// 32KB K-tile LDS (96 KB), 4 phases/K-tile, counted vmcnt(4) per K-tile.
__global__ __launch_bounds__(512) void gemm_v256(const unsigned short* __restrict__ A,
                          const unsigned short* __restrict__ Bt,
                          const float* __restrict__ bias,
                          unsigned short* __restrict__ Out) {
  __shared__ __align__(16) unsigned short lds[3][4][64][64];  // 96 KB
  const int t = threadIdx.x, l = t & 63, w = t >> 6;
  const int lr = l & 15, lg = l >> 4;
  const int wr = w >> 2, wc = w & 3;
  const int bid = blockIdx.x;
  const int swz = (bid & 7) * 32 + (bid >> 3);    // XCD swizzle (256 % 8 == 0)
  const int tn = swz & 1, tm = swz >> 1;

  const int swu = (t & 7) ^ ((t >> 3) & 7);
  const int row_g = 2 * (t >> 3) + (swu >> 2);
  const int col8 = (swu & 3) * 8;
  const unsigned short* Asrc = A + (size_t)(tm * 256 + row_g) * 512 + col8;
  const unsigned short* Bsrc = Bt + (size_t)(tn * 256 + row_g) * 512 + col8;

  const int rhalf = lr >> 1;
  const int fu = (((lr & 1) * 4 + lg) ^ rhalf) * 8;

  f32x4 acc[8][4] = {};

#define VSTAGE(blk, kt, buf)                                                   \
  {                                                                            \
    const unsigned short* s_ =                                                 \
        (((blk) < 2) ? (Asrc + (size_t)(blk) * 128 * 512)                      \
                     : (Bsrc + (size_t)((blk) - 2) * 128 * 512)) + (kt) * 32;  \
    gload16(s_, &lds[buf][blk][w * 8][0]);                                     \
  }

  VSTAGE(0, 0, 0) VSTAGE(1, 0, 0) VSTAGE(2, 0, 0) VSTAGE(3, 0, 0)
  VSTAGE(0, 1, 1) VSTAGE(1, 1, 1) VSTAGE(2, 1, 1) VSTAGE(3, 1, 1)
  asm volatile("s_waitcnt vmcnt(4)" ::: "memory");
  __builtin_amdgcn_s_barrier();
  asm volatile("" ::: "memory");

  for (int it = 0; it < 16; ++it) {
    const int cur = it % 3, stb = (it + 2) % 3;
    const int ktn = it + 2;
#pragma unroll
    for (int q = 0; q < 4; ++q) {
      const int mh = q >> 1, nh = q & 1;
      short8 af[4], bf[2];
#pragma unroll
      for (int mp = 0; mp < 4; ++mp)
        af[mp] = *(const short8*)&lds[cur][wr][(mh * 4 + mp) * 8 + rhalf][fu];
#pragma unroll
      for (int np = 0; np < 2; ++np)
        bf[np] = *(const short8*)&lds[cur][2 + (wc >> 1)][(wc & 1) * 32 + (nh * 2 + np) * 8 + rhalf][fu];
      if (it < 14) VSTAGE(q, ktn, stb)
      __builtin_amdgcn_s_setprio(1);
#pragma unroll
      for (int mp = 0; mp < 4; ++mp)
#pragma unroll
        for (int np = 0; np < 2; ++np)
          acc[mh * 4 + mp][nh * 2 + np] = __builtin_amdgcn_mfma_f32_16x16x32_bf16(
              af[mp], bf[np], acc[mh * 4 + mp][nh * 2 + np], 0, 0, 0);
      __builtin_amdgcn_s_setprio(0);
      asm volatile("" ::: "memory");
      if (q == 3) {
        if (it < 14) { asm volatile("s_waitcnt vmcnt(4)" ::: "memory"); }
        else         { asm volatile("s_waitcnt vmcnt(0)" ::: "memory"); }
      }
      __builtin_amdgcn_s_barrier();
      asm volatile("" ::: "memory");
    }
  }
#undef VSTAGE

  asm volatile("s_waitcnt vmcnt(0) lgkmcnt(0)" ::: "memory");
  const int c_base = tn * 256 + wc * 64;
  const int r_base = tm * 256 + wr * 128;
  const int b = r_base >> 12;
  float bv_[4];
#pragma unroll
  for (int n = 0; n < 4; ++n) bv_[n] = bias[c_base + n * 16 + lr];
#pragma unroll
  for (int n = 0; n < 4; ++n) {
    const int col = c_base + n * 16 + lr;
#pragma unroll
    for (int m = 0; m < 8; ++m) {
      const int row = r_base + m * 16 + lg * 4;
      const int nl = row & 4095;
      us4 v;
#pragma unroll
      for (int j = 0; j < 4; ++j) v[j] = f2bf(acc[m][n][j] + bv_[n]);
      *(us4*)&Out[((size_t)(b * 512 + col)) * 4096 + nl] = v;
    }
  }
}

// ---------------------------------------------------------------------------
// Partial context: D[v][k] = sum_tok VT[v][tok] * KeT[k][tok] over a 1024-token chunk.
__global__ void context_partial(const unsigned short* __restrict__ KeT,
                                const unsigned short* __restrict__ VT,
                                float* __restrict__ cp) {
  const int t = threadIdx.x, l = t & 63, w = t >> 6;
  const int lr = l & 15, lg = l >> 4;
  const int ch = blockIdx.x, h = blockIdx.y, b = blockIdx.z;
  const unsigned short* Kp = KeT + ((size_t)b * 512 + h * 64) * 4096;
  const unsigned short* Vp = VT + ((size_t)b * 512 + h * 64) * 4096;
  const int tok_w = ch * 1024 + w * 256;
  f32x4 acc[4][4] = {};
  for (int s = 0; s < 8; ++s) {
    const int tok = tok_w + s * 32 + lg * 8;
    short8 a[4], kf[4];
#pragma unroll
    for (int m = 0; m < 4; ++m) a[m] = *(const short8*)&Vp[(size_t)(m * 16 + lr) * 4096 + tok];
#pragma unroll
    for (int n = 0; n < 4; ++n) kf[n] = *(const short8*)&Kp[(size_t)(n * 16 + lr) * 4096 + tok];
#pragma unroll
    for (int m = 0; m < 4; ++m)
#pragma unroll
      for (int n = 0; n < 4; ++n)
        acc[m][n] = __builtin_amdgcn_mfma_f32_16x16x32_bf16(a[m], kf[n], acc[m][n], 0, 0, 0);
  }
  __shared__ float red[4][64][64];
#pragma unroll
  for (int m = 0; m < 4; ++m)
#pragma unroll
    for (int n = 0; n < 4; ++n)
#pragma unroll
      for (int j = 0; j < 4; ++j)
        red[w][m * 16 + lg * 4 + j][n * 16 + lr] = acc[m][n][j];
  __syncthreads();
  const int blk = (b * 8 + h) * 4 + ch;
  float* o = cp + (size_t)blk * 4096;
  for (int i = 0; i < 16; ++i) {
    int e = i * 256 + t;
    int v = e >> 6, k = e & 63;
    o[e] = red[0][v][k] + red[1][v][k] + red[2][v][k] + red[3][v][k];
  }
}

// ---------------------------------------------------------------------------
// Fused ctx_reduce + ctx_mm (R9, proven): per block (cc,h,b).
__global__ __launch_bounds__(256) void ctx_mm2(const float* __restrict__ cp,
                      const float* __restrict__ S, const unsigned short* __restrict__ Wrt,
                      unsigned short* __restrict__ MT) {
  __shared__ __align__(16) unsigned short ctx_lds[64][72];  // +8 pad
  const int t = threadIdx.x, l = t & 63, w = t >> 6;
  const int lr = l & 15, lg = l >> 4;
  const int cc = blockIdx.x, h = blockIdx.y, b = blockIdx.z;
  const int bh = b * 8 + h;

  const int k = t & 63, vg = t >> 6;
  const float rs = 1.0f / S[bh * 64 + k];
  const float* pb = cp + (size_t)bh * 4 * 4096 + k;
#pragma unroll
  for (int half = 0; half < 2; ++half) {
    short8 pkv;
#pragma unroll
    for (int i = 0; i < 8; ++i) {
      const int v = vg * 16 + half * 8 + i;
      const size_t e = (size_t)v * 64;
      float vsum = pb[e] + pb[4096 + e] + pb[8192 + e] + pb[12288 + e];
      pkv[i] = (short)f2bf(vsum * rs);
    }
    *(short8*)&ctx_lds[k][vg * 16 + half * 8] = pkv;
  }
  __syncthreads();

  const int c0 = cc * 128 + w * 32;
  f32x4 acc[4][2] = {};
#pragma unroll
  for (int kk = 0; kk < 2; ++kk) {
    const int vb = kk * 32 + lg * 8;
    short8 a[4], bfr[2];
#pragma unroll
    for (int m = 0; m < 4; ++m) a[m] = *(const short8*)&ctx_lds[m * 16 + lr][vb];
#pragma unroll
    for (int n = 0; n < 2; ++n)
      bfr[n] = *(const short8*)&Wrt[(size_t)(c0 + n * 16 + lr) * 512 + h * 64 + vb];
#pragma unroll
    for (int m = 0; m < 4; ++m)
#pragma unroll
      for (int n = 0; n < 2; ++n)
        acc[m][n] = __builtin_amdgcn_mfma_f32_16x16x32_bf16(a[m], bfr[n], acc[m][n], 0, 0, 0);
  }
#pragma unroll
  for (int n = 0; n < 2; ++n) {
    const int c = c0 + n * 16 + lr;
#pragma unroll
    for (int m = 0; m < 4; ++m) {
      const int kq = m * 16 + lg * 4;
      us4 v;
#pragma unroll
      for (int j = 0; j < 4; ++j) v[j] = f2bf(acc[m][n][j]);
      *(us4*)&MT[((size_t)b * 512 + c) * 512 + h * 64 + kq] = v;
    }
  }
}

// ---------------------------------------------------------------------------
extern "C" void kernel_launch(void* const* d_in, const int* in_sizes, int n_in,
                              void* d_out, int out_size, void* d_ws, size_t ws_size,
                              hipStream_t stream) {
  (void)in_sizes; (void)n_in; (void)out_size; (void)ws_size;
  const float* x  = (const float*)d_in[0];
  const float* y  = (const float*)d_in[1];
  const float* Wk = (const float*)d_in[2];
  const float* bk = (const float*)d_in[3];
  const float* Wq = (const float*)d_in[4];
  const float* bq = (const float*)d_in[5];
  const float* Wv = (const float*)d_in[6];
  const float* bv = (const float*)d_in[7];
  const float* Wr = (const float*)d_in[8];
  const float* br = (const float*)d_in[9];
  float* out = (float*)d_out;

  char* ws = (char*)d_ws;
  unsigned short* Wt   = (unsigned short*)(ws + 0);            //   2 MB: 4x [512][512] bf16
  unsigned short* xb   = (unsigned short*)(ws + 2097152);      //  32 MB: bf16(x)
  unsigned short* yb   = (unsigned short*)(ws + 35651584);     //  32 MB: bf16(y)
  unsigned short* xyb  = (unsigned short*)(ws + 69206016);     //  32 MB: bf16(x+y); reused as Qp
  unsigned short* KeT  = (unsigned short*)(ws + 102760448);    //  32 MB: [B][512][4096] bf16
  unsigned short* VT   = (unsigned short*)(ws + 136314880);    //  32 MB: [B][512][4096] bf16
  float* S             = (float*)(ws + 169869312);             //  16 KB
  float* cp            = (float*)(ws + 169885696);             //   4 MB
  unsigned short* MT   = (unsigned short*)(ws + 174080000);    //   4 MB (ends ~178.3 MB)
  unsigned short* Qp   = xyb;                                  // xyb dead after gemm_bf16<0>

  prep_w<<<dim3(8, 8, 4), 256, 0, stream>>>(Wk, Wq, Wv, Wr, Wt, S);
  prep_xy<<<16384, 256, 0, stream>>>(x, y, xb, yb, xyb);
  gemm_bf16<0><<<1024, 256, 0, stream>>>(xyb, Wt, bk, KeT, S);
  gemm_v256<<<256, 512, 0, stream>>>(xb, Wt + 2 * 262144, bv, VT);
  gemm_bf16<1><<<1024, 256, 0, stream>>>(yb, Wt + 262144, bq, Qp, nullptr);
  context_partial<<<dim3(4, 8, 8), 256, 0, stream>>>(KeT, VT, cp);
  ctx_mm2<<<dim3(4, 8, 8), 256, 0, stream>>>(cp, S, Wt + 3 * 262144, MT);
  gemm_bf16<3><<<1024, 256, 0, stream>>>(Qp, MT, br, out, nullptr);
}